// Round 4
// baseline (442.129 us; speedup 1.0000x reference)
//
#include <hip/hip_runtime.h>

// Wav2Vec2 Gumbel VQ — round 4: K-chunked LDS (64 KiB) -> 2 blocks/CU for
// latency hiding + GEMM/epilogue phase overlap across resident blocks.

#define GG   2
#define KK   320
#define NN   65536
#define DD   512
#define DPG  128
#define EPSL 1e-7f

typedef __attribute__((ext_vector_type(8))) _Float16 f16x8;
typedef __attribute__((ext_vector_type(4))) float    f32x4;

// ---------- prep: W (640x512 f32) -> fragment-ordered f16 hi/lo ----------
// Wf element offset for (ct,t,p,l,j) = ((ct*16+t)*2+p)*512 + l*8 + j
// frag: col = 16*ct + (l&15), k = 32*t + 8*(l>>4) + j   (B-frag layout, verified r2)
__global__ __launch_bounds__(256) void prep_w(const float* __restrict__ W,
                                              _Float16* __restrict__ Wf) {
    int gt = blockIdx.x * 256 + threadIdx.x;          // 40960 threads
    int w  = gt >> 6, l = gt & 63;                    // w = ct*16 + t
    int col = 16 * (w >> 4) + (l & 15);
    int k0  = 32 * (w & 15) + 8 * (l >> 4);
    const float* src = W + (size_t)col * DD + k0;
    float4 v0 = *(const float4*)(src);
    float4 v1 = *(const float4*)(src + 4);
    float vv[8] = {v0.x, v0.y, v0.z, v0.w, v1.x, v1.y, v1.z, v1.w};
    f16x8 hi, lo;
#pragma unroll
    for (int j = 0; j < 8; ++j) {
        _Float16 h = (_Float16)vv[j];
        hi[j] = h;
        lo[j] = (_Float16)(vv[j] - (float)h);
    }
    size_t base = (size_t)w * 1024 + (size_t)l * 8;
    *(f16x8*)(Wf + base)       = hi;
    *(f16x8*)(Wf + base + 512) = lo;
}

// ---------- main fused kernel ----------
// grid: 1024 blocks (64 rows each, ALL 640 cols). 512 thr = 8 waves.
// wave w: group g=w>>2, col-quarter hc=w&3 -> cols g*320 + hc*80..+79 (5 cf), rows 0..63 (4 rf).
// A tile staged in TWO 256-k chunks through one 64 KiB buffer -> 2 blocks/CU.
__global__ __launch_bounds__(512, 4) void vq_main(
    const float* __restrict__ H, const int* __restrict__ mask,
    const float* __restrict__ gumbel, const _Float16* __restrict__ Wf,
    const float* __restrict__ bias, const float* __restrict__ cv,
    float* __restrict__ out, float* __restrict__ marg)
{
    // chunk: frag f = rf*8 + tl covers rows 16rf..+15, k = 256*half + 32*tl..+31
    __shared__ __align__(16) _Float16 Albuf[32][2][64][8];   // 64 KiB
    __shared__ float red_m[512], red_s[512], red_z[512];
    __shared__ int   red_i[512];
    __shared__ float mfin[128], wrowS[128];
    __shared__ int   idxf[128];

    const int tid = threadIdx.x;
    const int l   = tid & 63, w = tid >> 6;
    const int g   = w >> 2,  hc = w & 3;
    const int n0  = blockIdx.x * 64;
    const int q   = l >> 4,  ln = l & 15;

    f32x4 acc[4][5];
    const f32x4 vzero = {0.f, 0.f, 0.f, 0.f};
#pragma unroll
    for (int a = 0; a < 4; ++a)
#pragma unroll
        for (int b = 0; b < 5; ++b) acc[a][b] = vzero;

    const _Float16* Wb = Wf + (size_t)(g * 20 + hc * 5) * 16384 + (size_t)l * 8;

    for (int half = 0; half < 2; ++half) {
        if (half) __syncthreads();       // all reads of prev chunk complete

        // ---- stage chunk: wave w converts frags 4w..4w+3 (conflict-free b128 writes) ----
#pragma unroll
        for (int i = 0; i < 4; ++i) {
            const int f = 4 * w + i;
            const int rf = f >> 3, tl = f & 7;
            const float* src = H + (size_t)(n0 + 16 * rf + ln) * DD + 256 * half + 32 * tl + 8 * q;
            float4 v0 = *(const float4*)src;
            float4 v1 = *(const float4*)(src + 4);
            float vv[8] = {v0.x, v0.y, v0.z, v0.w, v1.x, v1.y, v1.z, v1.w};
            f16x8 hi, lo;
#pragma unroll
            for (int j = 0; j < 8; ++j) {
                _Float16 h = (_Float16)vv[j];
                hi[j] = h;
                lo[j] = (_Float16)(vv[j] - (float)h);
            }
            *(f16x8*)&Albuf[f][0][l][0] = hi;
            *(f16x8*)&Albuf[f][1][l][0] = lo;
        }
        __syncthreads();

        // ---- K-loop over this chunk ----
        for (int tl = 0; tl < 8; ++tl) {
            const int t = 8 * half + tl;
            f16x8 Bh[5], Bl[5];
#pragma unroll
            for (int cf = 0; cf < 5; ++cf) {
                const _Float16* wp = Wb + (size_t)cf * 16384 + (size_t)t * 1024;
                Bh[cf] = *(const f16x8*)wp;
                Bl[cf] = *(const f16x8*)(wp + 512);
            }
            f16x8 Ah[4], Al[4];
#pragma unroll
            for (int rf = 0; rf < 4; ++rf) {
                Ah[rf] = *(const f16x8*)&Albuf[rf * 8 + tl][0][l][0];
                Al[rf] = *(const f16x8*)&Albuf[rf * 8 + tl][1][l][0];
            }
#pragma unroll
            for (int cf = 0; cf < 5; ++cf)
#pragma unroll
                for (int rf = 0; rf < 4; ++rf) {
                    acc[rf][cf] = __builtin_amdgcn_mfma_f32_16x16x32_f16(Ah[rf], Bh[cf], acc[rf][cf], 0, 0, 0);
                    acc[rf][cf] = __builtin_amdgcn_mfma_f32_16x16x32_f16(Ah[rf], Bl[cf], acc[rf][cf], 0, 0, 0);
                    acc[rf][cf] = __builtin_amdgcn_mfma_f32_16x16x32_f16(Al[rf], Bh[cf], acc[rf][cf], 0, 0, 0);
                }
        }
    }

    // ---- bias ----
#pragma unroll
    for (int cf = 0; cf < 5; ++cf) {
        float bb = bias[g * KK + hc * 80 + 16 * cf + ln];
#pragma unroll
        for (int rf = 0; rf < 4; ++rf) {
            acc[rf][cf][0] += bb; acc[rf][cf][1] += bb;
            acc[rf][cf][2] += bb; acc[rf][cf][3] += bb;
        }
    }

    // ---- per-row stats over this wave's 80 cols (16-lane shfl reduce) ----
#pragma unroll
    for (int rf = 0; rf < 4; ++rf) {
#pragma unroll
        for (int reg = 0; reg < 4; ++reg) {
            const int row = 16 * rf + 4 * q + reg;
            const float* gp = gumbel + ((size_t)(n0 + row) * GG + g) * KK + hc * 80 + ln;
            float lm = -3.0e38f, zm = -3.0e38f;
            int zi = 0;
#pragma unroll
            for (int cf = 0; cf < 5; ++cf) {
                float v = acc[rf][cf][reg];
                lm = fmaxf(lm, v);
                float z = v + gp[16 * cf];
                if (z > zm) { zm = z; zi = hc * 80 + 16 * cf + ln; }  // first-index tie rule
            }
#pragma unroll
            for (int d = 1; d <= 8; d <<= 1) {
                lm = fmaxf(lm, __shfl_xor(lm, d));
                float zo = __shfl_xor(zm, d);
                int   io = __shfl_xor(zi, d);
                if (zo > zm || (zo == zm && io < zi)) { zm = zo; zi = io; }
            }
            float s = 0.f;
#pragma unroll
            for (int cf = 0; cf < 5; ++cf) s += __expf(acc[rf][cf][reg] - lm);
#pragma unroll
            for (int d = 1; d <= 8; d <<= 1) s += __shfl_xor(s, d);
            if (ln == 0) {
                const int base = (g * 64 + row) * 4 + hc;
                red_m[base] = lm; red_s[base] = s;
                red_z[base] = zm; red_i[base] = zi;
            }
        }
    }
    __syncthreads();

    // ---- combine 4 col-quarters per (group,row) ----
    if (tid < 128) {
        const int gg = tid >> 6, r = tid & 63;
        const int b0 = (gg * 64 + r) * 4;
        float m = red_m[b0];
        m = fmaxf(m, red_m[b0 + 1]); m = fmaxf(m, red_m[b0 + 2]); m = fmaxf(m, red_m[b0 + 3]);
        float Z = 0.f;
        float zb = -3.0e38f; int ib = 0;
#pragma unroll
        for (int h = 0; h < 4; ++h) {
            Z += red_s[b0 + h] * __expf(red_m[b0 + h] - m);
            if (red_z[b0 + h] > zb) { zb = red_z[b0 + h]; ib = red_i[b0 + h]; }  // ascending h: first max wins
        }
        idxf[gg * 64 + r]  = ib;
        mfin[gg * 64 + r]  = m;
        wrowS[gg * 64 + r] = ((mask[n0 + r] != 0) ? 1.0f : 0.0f) / Z;
    }
    __syncthreads();

    // ---- marginal: per-col partials over this block's 64 rows ----
    float cs[5] = {0.f, 0.f, 0.f, 0.f, 0.f};
#pragma unroll
    for (int rf = 0; rf < 4; ++rf) {
#pragma unroll
        for (int reg = 0; reg < 4; ++reg) {
            const int row = 16 * rf + 4 * q + reg;
            const float mf = mfin[g * 64 + row], wv = wrowS[g * 64 + row];
#pragma unroll
            for (int cf = 0; cf < 5; ++cf)
                cs[cf] += __expf(acc[rf][cf][reg] - mf) * wv;
        }
    }
#pragma unroll
    for (int cf = 0; cf < 5; ++cf) {
        float v = cs[cf];
        v += __shfl_xor(v, 16);
        v += __shfl_xor(v, 32);
        if (l < 16) atomicAdd(&marg[g * KK + hc * 80 + 16 * cf + l], v);
    }

    // ---- codevector gather ----
    for (int e = tid; e < 64 * 256; e += 512) {
        const int row = e >> 8, c = e & 255, gg = c >> 7, d = c & 127;
        out[(size_t)(n0 + row) * 256 + c] =
            cv[((size_t)gg * KK + idxf[gg * 64 + row]) * DPG + d];
    }
}

// ---------- perplexity finalize ----------
__global__ __launch_bounds__(256) void finalize_kernel(
    const int* __restrict__ mask, const float* __restrict__ marg,
    float* __restrict__ perp_out)
{
    __shared__ float red[256];
    __shared__ float hg[GG];
    const int tid = threadIdx.x;

    int cnt = 0;
    for (int n = tid; n < NN; n += 256) cnt += (mask[n] != 0) ? 1 : 0;
    red[tid] = (float)cnt;
    __syncthreads();
    for (int s = 128; s > 0; s >>= 1) {
        if (tid < s) red[tid] += red[tid + s];
        __syncthreads();
    }
    const float invc = 1.0f / red[0];
    __syncthreads();

    for (int g = 0; g < GG; ++g) {
        float h = 0.0f;
        for (int c = tid; c < KK; c += 256) {
            float m = marg[g * KK + c] * invc;
            h += m * logf(m + EPSL);
        }
        red[tid] = h;
        __syncthreads();
        for (int s = 128; s > 0; s >>= 1) {
            if (tid < s) red[tid] += red[tid + s];
            __syncthreads();
        }
        if (tid == 0) hg[g] = red[0];
        __syncthreads();
    }
    if (tid == 0) perp_out[0] = expf(-hg[0]) + expf(-hg[1]);
}

extern "C" void kernel_launch(void* const* d_in, const int* in_sizes, int n_in,
                              void* d_out, int out_size, void* d_ws, size_t ws_size,
                              hipStream_t stream)
{
    const float* H      = (const float*)d_in[0];   // (32,2048,512) f32
    const int*   mask   = (const int*)d_in[1];     // (32,2048) bool->int32
    const float* gumbel = (const float*)d_in[2];   // (131072,320) f32
    const float* W      = (const float*)d_in[3];   // (640,512) f32
    const float* bias   = (const float*)d_in[4];   // (640,) f32
    const float* cv     = (const float*)d_in[5];   // (1,640,128) f32

    float*     out  = (float*)d_out;               // 16777216 + 1 floats
    float*     marg = (float*)d_ws;                // 640 f32 accumulator
    _Float16*  Wf   = (_Float16*)((char*)d_ws + 4096);  // 1.31 MB f16 frags

    hipMemsetAsync(marg, 0, GG * KK * sizeof(float), stream);
    prep_w<<<160, 256, 0, stream>>>(W, Wf);
    vq_main<<<1024, 512, 0, stream>>>(H, mask, gumbel, Wf, bias, cv, out, marg);
    finalize_kernel<<<1, 256, 0, stream>>>(mask, marg, out + (size_t)NN * GG * DPG);
}

// Round 5
// 309.297 us; speedup vs baseline: 1.4295x; 1.4295x over previous
//
#include <hip/hip_runtime.h>

// Wav2Vec2 Gumbel VQ — round 5: single-bf16 MFMA (threshold analysis shows hi/lo
// split unnecessary), 32-row blocks, barrier-free GEMM with direct-global A +
// v_perm bf16 pack, register double-buffer, <=128 VGPR -> 2 blocks/CU.

#define GG   2
#define KK   320
#define NN   65536
#define DD   512
#define DPG  128
#define EPSL 1e-7f

typedef __attribute__((ext_vector_type(8))) short bf16x8;   // 8 x bf16
typedef __attribute__((ext_vector_type(4))) float f32x4;

static __device__ __forceinline__ unsigned short f2bf_rne(float f) {
    unsigned u = __float_as_uint(f);
    u += 0x7FFFu + ((u >> 16) & 1u);
    return (unsigned short)(u >> 16);
}

// pack 8 f32 (two float4, consecutive k) -> bf16x8 via v_perm (truncation)
static __device__ __forceinline__ bf16x8 pack8(float4 v0, float4 v1) {
    union { int i[4]; bf16x8 b; } u;
    u.i[0] = __builtin_amdgcn_perm(__float_as_uint(v0.y), __float_as_uint(v0.x), 0x07060302);
    u.i[1] = __builtin_amdgcn_perm(__float_as_uint(v0.w), __float_as_uint(v0.z), 0x07060302);
    u.i[2] = __builtin_amdgcn_perm(__float_as_uint(v1.y), __float_as_uint(v1.x), 0x07060302);
    u.i[3] = __builtin_amdgcn_perm(__float_as_uint(v1.w), __float_as_uint(v1.z), 0x07060302);
    return u.b;
}

// ---------- prep: W (640x512 f32) -> fragment-ordered bf16 (RNE) ----------
// w = ct*16 + t; element (w*512 + l*8 + j) = W[col=16ct+(l&15)][k=32t+8(l>>4)+j]
__global__ __launch_bounds__(256) void prep_w(const float* __restrict__ W,
                                              short* __restrict__ Wf) {
    int gt = blockIdx.x * 256 + threadIdx.x;          // 40960 threads
    int w  = gt >> 6, l = gt & 63;
    int col = 16 * (w >> 4) + (l & 15);
    int k0  = 32 * (w & 15) + 8 * (l >> 4);
    const float* src = W + (size_t)col * DD + k0;
    float4 v0 = *(const float4*)(src);
    float4 v1 = *(const float4*)(src + 4);
    float vv[8] = {v0.x, v0.y, v0.z, v0.w, v1.x, v1.y, v1.z, v1.w};
    union { short s[8]; bf16x8 b; } u;
#pragma unroll
    for (int j = 0; j < 8; ++j) u.s[j] = (short)f2bf_rne(vv[j]);
    *(bf16x8*)(Wf + (size_t)w * 512 + (size_t)l * 8) = u.b;
}

// ---------- main fused kernel ----------
// grid: 2048 blocks (32 rows each, ALL 640 cols). 512 thr = 8 waves.
// wave w: group g=w>>2, quarter hc=w&3 -> cols g*320+hc*80..+79 (5 cf), rows 0..31 (2 rf).
__global__ __launch_bounds__(512, 4) void vq_main(
    const float* __restrict__ H, const int* __restrict__ mask,
    const float* __restrict__ gumbel, const short* __restrict__ Wf,
    const float* __restrict__ bias, const float* __restrict__ cv,
    float* __restrict__ out, float* __restrict__ marg)
{
    __shared__ float red_m[256], red_s[256], red_z[256];
    __shared__ int   red_i[256];
    __shared__ float mfin[64], wrowS[64];
    __shared__ int   idxf[64];

    const int tid = threadIdx.x;
    const int l   = tid & 63, w = tid >> 6;
    const int g   = w >> 2,  hc = w & 3;
    const int n0  = blockIdx.x * 32;
    const int q   = l >> 4,  ln = l & 15;
    const int ct0 = g * 20 + hc * 5;

    // per-lane A row bases (float4 units): row = n0 + 16*rf + ln, k-offset 8*q
    const float4* Ha4[2];
    Ha4[0] = (const float4*)(H + (size_t)(n0 + ln) * DD) + 2 * q;
    Ha4[1] = (const float4*)(H + (size_t)(n0 + 16 + ln) * DD) + 2 * q;
    const bf16x8* Wb8 = (const bf16x8*)Wf + l;   // + ((ct0+cf)*16+t)*64

    f32x4 acc[2][5];
    const f32x4 vzero = {0.f, 0.f, 0.f, 0.f};
#pragma unroll
    for (int a = 0; a < 2; ++a)
#pragma unroll
        for (int b = 0; b < 5; ++b) acc[a][b] = vzero;

    bf16x8 Bc[5], Ac[2], Bn[5], An[2];
#pragma unroll
    for (int cf = 0; cf < 5; ++cf) Bc[cf] = Wb8[(size_t)((ct0 + cf) * 16) * 64];
#pragma unroll
    for (int rf = 0; rf < 2; ++rf) Ac[rf] = pack8(Ha4[rf][0], Ha4[rf][1]);

#pragma unroll
    for (int t = 0; t < 16; ++t) {
        if (t < 15) {
#pragma unroll
            for (int cf = 0; cf < 5; ++cf)
                Bn[cf] = Wb8[(size_t)((ct0 + cf) * 16 + t + 1) * 64];
#pragma unroll
            for (int rf = 0; rf < 2; ++rf)
                An[rf] = pack8(Ha4[rf][8 * (t + 1)], Ha4[rf][8 * (t + 1) + 1]);
        }
#pragma unroll
        for (int cf = 0; cf < 5; ++cf)
#pragma unroll
            for (int rf = 0; rf < 2; ++rf)
                acc[rf][cf] = __builtin_amdgcn_mfma_f32_16x16x32_bf16(Ac[rf], Bc[cf], acc[rf][cf], 0, 0, 0);
        if (t < 15) {
#pragma unroll
            for (int cf = 0; cf < 5; ++cf) Bc[cf] = Bn[cf];
#pragma unroll
            for (int rf = 0; rf < 2; ++rf) Ac[rf] = An[rf];
        }
    }

    // ---- bias ----
#pragma unroll
    for (int cf = 0; cf < 5; ++cf) {
        float bb = bias[g * KK + hc * 80 + 16 * cf + ln];
#pragma unroll
        for (int rf = 0; rf < 2; ++rf) {
            acc[rf][cf][0] += bb; acc[rf][cf][1] += bb;
            acc[rf][cf][2] += bb; acc[rf][cf][3] += bb;
        }
    }

    // ---- per-row stats over this wave's 80 cols (16-lane shfl reduce) ----
#pragma unroll
    for (int rf = 0; rf < 2; ++rf) {
#pragma unroll
        for (int reg = 0; reg < 4; ++reg) {
            const int row = 16 * rf + 4 * q + reg;
            const float* gp = gumbel + ((size_t)(n0 + row) * GG + g) * KK + hc * 80 + ln;
            float lm = -3.0e38f, zm = -3.0e38f;
            int zi = 0;
#pragma unroll
            for (int cf = 0; cf < 5; ++cf) {
                float v = acc[rf][cf][reg];
                lm = fmaxf(lm, v);
                float z = v + gp[16 * cf];
                if (z > zm) { zm = z; zi = hc * 80 + 16 * cf + ln; }  // first-index tie rule
            }
#pragma unroll
            for (int d = 1; d <= 8; d <<= 1) {
                lm = fmaxf(lm, __shfl_xor(lm, d));
                float zo = __shfl_xor(zm, d);
                int   io = __shfl_xor(zi, d);
                if (zo > zm || (zo == zm && io < zi)) { zm = zo; zi = io; }
            }
            float s = 0.f;
#pragma unroll
            for (int cf = 0; cf < 5; ++cf) s += __expf(acc[rf][cf][reg] - lm);
#pragma unroll
            for (int d = 1; d <= 8; d <<= 1) s += __shfl_xor(s, d);
            if (ln == 0) {
                const int base = (g * 32 + row) * 4 + hc;
                red_m[base] = lm; red_s[base] = s;
                red_z[base] = zm; red_i[base] = zi;
            }
        }
    }
    __syncthreads();

    // ---- combine 4 col-quarters per (group,row) ----
    if (tid < 64) {
        const int gg = tid >> 5, r = tid & 31;
        const int b0 = (gg * 32 + r) * 4;
        float m = red_m[b0];
        m = fmaxf(m, red_m[b0 + 1]); m = fmaxf(m, red_m[b0 + 2]); m = fmaxf(m, red_m[b0 + 3]);
        float Z = 0.f;
        float zb = -3.0e38f; int ib = 0;
#pragma unroll
        for (int h = 0; h < 4; ++h) {
            Z += red_s[b0 + h] * __expf(red_m[b0 + h] - m);
            if (red_z[b0 + h] > zb) { zb = red_z[b0 + h]; ib = red_i[b0 + h]; }  // ascending h: first max wins
        }
        idxf[gg * 32 + r]  = ib;
        mfin[gg * 32 + r]  = m;
        wrowS[gg * 32 + r] = ((mask[n0 + r] != 0) ? 1.0f : 0.0f) / Z;
    }
    __syncthreads();

    // ---- marginal: per-col partials over this block's 32 rows ----
    float cs[5] = {0.f, 0.f, 0.f, 0.f, 0.f};
#pragma unroll
    for (int rf = 0; rf < 2; ++rf) {
#pragma unroll
        for (int reg = 0; reg < 4; ++reg) {
            const int row = 16 * rf + 4 * q + reg;
            const float mf = mfin[g * 32 + row], wv = wrowS[g * 32 + row];
#pragma unroll
            for (int cf = 0; cf < 5; ++cf)
                cs[cf] += __expf(acc[rf][cf][reg] - mf) * wv;
        }
    }
#pragma unroll
    for (int cf = 0; cf < 5; ++cf) {
        float v = cs[cf];
        v += __shfl_xor(v, 16);
        v += __shfl_xor(v, 32);
        if (l < 16) atomicAdd(&marg[g * KK + hc * 80 + 16 * cf + l], v);
    }

    // ---- codevector gather ----
    for (int e = tid; e < 32 * 256; e += 512) {
        const int row = e >> 8, c = e & 255, gg = c >> 7, d = c & 127;
        out[(size_t)(n0 + row) * 256 + c] =
            cv[((size_t)gg * KK + idxf[gg * 32 + row]) * DPG + d];
    }
}

// ---------- perplexity finalize ----------
__global__ __launch_bounds__(256) void finalize_kernel(
    const int* __restrict__ mask, const float* __restrict__ marg,
    float* __restrict__ perp_out)
{
    __shared__ float red[256];
    __shared__ float hg[GG];
    const int tid = threadIdx.x;

    int cnt = 0;
    for (int n = tid; n < NN; n += 256) cnt += (mask[n] != 0) ? 1 : 0;
    red[tid] = (float)cnt;
    __syncthreads();
    for (int s = 128; s > 0; s >>= 1) {
        if (tid < s) red[tid] += red[tid + s];
        __syncthreads();
    }
    const float invc = 1.0f / red[0];
    __syncthreads();

    for (int g = 0; g < GG; ++g) {
        float h = 0.0f;
        for (int c = tid; c < KK; c += 256) {
            float m = marg[g * KK + c] * invc;
            h += m * logf(m + EPSL);
        }
        red[tid] = h;
        __syncthreads();
        for (int s = 128; s > 0; s >>= 1) {
            if (tid < s) red[tid] += red[tid + s];
            __syncthreads();
        }
        if (tid == 0) hg[g] = red[0];
        __syncthreads();
    }
    if (tid == 0) perp_out[0] = expf(-hg[0]) + expf(-hg[1]);
}

extern "C" void kernel_launch(void* const* d_in, const int* in_sizes, int n_in,
                              void* d_out, int out_size, void* d_ws, size_t ws_size,
                              hipStream_t stream)
{
    const float* H      = (const float*)d_in[0];   // (32,2048,512) f32
    const int*   mask   = (const int*)d_in[1];     // (32,2048) bool->int32
    const float* gumbel = (const float*)d_in[2];   // (131072,320) f32
    const float* W      = (const float*)d_in[3];   // (640,512) f32
    const float* bias   = (const float*)d_in[4];   // (640,) f32
    const float* cv     = (const float*)d_in[5];   // (1,640,128) f32

    float*  out  = (float*)d_out;                  // 16777216 + 1 floats
    float*  marg = (float*)d_ws;                   // 640 f32 accumulator
    short*  Wf   = (short*)((char*)d_ws + 4096);   // 0.66 MB bf16 frags

    hipMemsetAsync(marg, 0, GG * KK * sizeof(float), stream);
    prep_w<<<160, 256, 0, stream>>>(W, Wf);
    vq_main<<<2048, 512, 0, stream>>>(H, mask, gumbel, Wf, bias, cv, out, marg);
    finalize_kernel<<<1, 256, 0, stream>>>(mask, marg, out + (size_t)NN * GG * DPG);
}

// Round 6
// 172.598 us; speedup vs baseline: 2.5616x; 1.7920x over previous
//
#include <hip/hip_runtime.h>

// Wav2Vec2 Gumbel VQ — round 6: bf16 MFMA with LDS A-tile + sched_barrier-pinned
// B register ping-pong (compiler defeated source prefetch in r5: VGPR=52) +
// batched epilogue loads. 32-row blocks, 512 thr, <=128 VGPR -> 2 blocks/CU.

#define GG   2
#define KK   320
#define NN   65536
#define DD   512
#define DPG  128
#define EPSL 1e-7f

typedef __attribute__((ext_vector_type(8))) short bf16x8;   // 8 x bf16
typedef __attribute__((ext_vector_type(4))) float f32x4;

static __device__ __forceinline__ unsigned short f2bf_rne(float f) {
    unsigned u = __float_as_uint(f);
    u += 0x7FFFu + ((u >> 16) & 1u);
    return (unsigned short)(u >> 16);
}

static __device__ __forceinline__ bf16x8 pack8_rne(float4 v0, float4 v1) {
    union { unsigned short s[8]; bf16x8 b; } u;
    u.s[0] = f2bf_rne(v0.x); u.s[1] = f2bf_rne(v0.y);
    u.s[2] = f2bf_rne(v0.z); u.s[3] = f2bf_rne(v0.w);
    u.s[4] = f2bf_rne(v1.x); u.s[5] = f2bf_rne(v1.y);
    u.s[6] = f2bf_rne(v1.z); u.s[7] = f2bf_rne(v1.w);
    return u.b;
}

// ---------- prep: W (640x512 f32) -> fragment-ordered bf16 (RNE) ----------
// w = ct*16 + t; element (w*512 + l*8 + j) = W[col=16ct+(l&15)][k=32t+8(l>>4)+j]
__global__ __launch_bounds__(256) void prep_w(const float* __restrict__ W,
                                              short* __restrict__ Wf) {
    int gt = blockIdx.x * 256 + threadIdx.x;          // 40960 threads
    int w  = gt >> 6, l = gt & 63;
    int col = 16 * (w >> 4) + (l & 15);
    int k0  = 32 * (w & 15) + 8 * (l >> 4);
    const float* src = W + (size_t)col * DD + k0;
    float4 v0 = *(const float4*)(src);
    float4 v1 = *(const float4*)(src + 4);
    *(bf16x8*)(Wf + (size_t)w * 512 + (size_t)l * 8) = pack8_rne(v0, v1);
}

// ---------- main fused kernel ----------
// grid: 2048 blocks (32 rows each, ALL 640 cols). 512 thr = 8 waves.
// wave w: group g=w>>2, quarter hc=w&3 -> cols g*320+hc*80..+79 (5 cf), rows 0..31 (2 rf).
__global__ __launch_bounds__(512, 4) void vq_main(
    const float* __restrict__ H, const int* __restrict__ mask,
    const float* __restrict__ gumbel, const short* __restrict__ Wf,
    const float* __restrict__ bias, const float* __restrict__ cv,
    float* __restrict__ out, float* __restrict__ marg)
{
    // A tile, fragment-ordered: frag f = rf*16 + t, lane slot l -> 16 B. 32 KB.
    __shared__ __align__(16) bf16x8 Alds[32][64];
    __shared__ float red_m[256], red_s[256], red_z[256];
    __shared__ int   red_i[256];
    __shared__ float mfin[64], wrowS[64];
    __shared__ int   idxf[64];

    const int tid = threadIdx.x;
    const int l   = tid & 63, w = tid >> 6;
    const int g   = w >> 2,  hc = w & 3;
    const int n0  = blockIdx.x * 32;
    const int q   = l >> 4,  ln = l & 15;
    const int ct0 = g * 20 + hc * 5;

    // ---- stage A tile: 2048 frag-lane slots / 512 threads = 4 each ----
#pragma unroll
    for (int i = 0; i < 4; ++i) {
        const int s  = tid + 512 * i;
        const int f  = s >> 6, sl = s & 63;
        const int rf = f >> 4, t = f & 15;
        const float* src = H + (size_t)(n0 + 16 * rf + (sl & 15)) * DD + 32 * t + 8 * (sl >> 4);
        float4 v0 = *(const float4*)src;
        float4 v1 = *(const float4*)(src + 4);
        Alds[f][sl] = pack8_rne(v0, v1);
    }
    __syncthreads();

    // ---- GEMM: B reg ping-pong pinned by sched_barrier, A from LDS ----
    f32x4 acc[2][5];
    const f32x4 vzero = {0.f, 0.f, 0.f, 0.f};
#pragma unroll
    for (int a = 0; a < 2; ++a)
#pragma unroll
        for (int b = 0; b < 5; ++b) acc[a][b] = vzero;

    const bf16x8* Wb8 = (const bf16x8*)Wf + l;   // + ((ct0+cf)*16+t)*64

    bf16x8 B0[5], B1[5], A0[2], A1[2];

#define LOADB(dst, t_)                                                         \
    { _Pragma("unroll")                                                        \
      for (int cf = 0; cf < 5; ++cf)                                           \
          dst[cf] = Wb8[(size_t)((ct0 + cf) * 16 + (t_)) * 64]; }
#define LOADA(dst, t_)                                                         \
    { dst[0] = Alds[(t_)][l]; dst[1] = Alds[16 + (t_)][l]; }
#define MFMA10(Ar, Br)                                                         \
    { _Pragma("unroll")                                                        \
      for (int cf = 0; cf < 5; ++cf) {                                         \
          acc[0][cf] = __builtin_amdgcn_mfma_f32_16x16x32_bf16(Ar[0], Br[cf], acc[0][cf], 0, 0, 0); \
          acc[1][cf] = __builtin_amdgcn_mfma_f32_16x16x32_bf16(Ar[1], Br[cf], acc[1][cf], 0, 0, 0); } }

    LOADB(B0, 0) LOADA(A0, 0)
#pragma unroll 1
    for (int tt = 0; tt < 7; ++tt) {
        LOADB(B1, 2 * tt + 1) LOADA(A1, 2 * tt + 1)
        __builtin_amdgcn_sched_barrier(0);
        MFMA10(A0, B0)
        __builtin_amdgcn_sched_barrier(0);
        LOADB(B0, 2 * tt + 2) LOADA(A0, 2 * tt + 2)
        __builtin_amdgcn_sched_barrier(0);
        MFMA10(A1, B1)
        __builtin_amdgcn_sched_barrier(0);
    }
    LOADB(B1, 15) LOADA(A1, 15)
    __builtin_amdgcn_sched_barrier(0);
    MFMA10(A0, B0)
    __builtin_amdgcn_sched_barrier(0);
    MFMA10(A1, B1)

    // ---- batched epilogue loads: bias + all 40 gumbel values, then fence ----
    float bb[5];
#pragma unroll
    for (int cf = 0; cf < 5; ++cf) bb[cf] = bias[g * KK + hc * 80 + 16 * cf + ln];

    float gum[8][5];
#pragma unroll
    for (int rf = 0; rf < 2; ++rf)
#pragma unroll
        for (int reg = 0; reg < 4; ++reg) {
            const int row = 16 * rf + 4 * q + reg;
            const float* gp = gumbel + ((size_t)(n0 + row) * GG + g) * KK + hc * 80 + ln;
#pragma unroll
            for (int cf = 0; cf < 5; ++cf) gum[rf * 4 + reg][cf] = gp[16 * cf];
        }
    __builtin_amdgcn_sched_barrier(0);

    // ---- bias ----
#pragma unroll
    for (int cf = 0; cf < 5; ++cf)
#pragma unroll
        for (int rf = 0; rf < 2; ++rf) {
            acc[rf][cf][0] += bb[cf]; acc[rf][cf][1] += bb[cf];
            acc[rf][cf][2] += bb[cf]; acc[rf][cf][3] += bb[cf];
        }

    // ---- per-row stats over this wave's 80 cols (16-lane shfl reduce) ----
#pragma unroll
    for (int rf = 0; rf < 2; ++rf) {
#pragma unroll
        for (int reg = 0; reg < 4; ++reg) {
            const int row = 16 * rf + 4 * q + reg;
            float lm = -3.0e38f, zm = -3.0e38f;
            int zi = 0;
#pragma unroll
            for (int cf = 0; cf < 5; ++cf) {
                float v = acc[rf][cf][reg];
                lm = fmaxf(lm, v);
                float z = v + gum[rf * 4 + reg][cf];
                if (z > zm) { zm = z; zi = hc * 80 + 16 * cf + ln; }  // first-index tie rule
            }
#pragma unroll
            for (int d = 1; d <= 8; d <<= 1) {
                lm = fmaxf(lm, __shfl_xor(lm, d));
                float zo = __shfl_xor(zm, d);
                int   io = __shfl_xor(zi, d);
                if (zo > zm || (zo == zm && io < zi)) { zm = zo; zi = io; }
            }
            float s = 0.f;
#pragma unroll
            for (int cf = 0; cf < 5; ++cf) s += __expf(acc[rf][cf][reg] - lm);
#pragma unroll
            for (int d = 1; d <= 8; d <<= 1) s += __shfl_xor(s, d);
            if (ln == 0) {
                const int base = (g * 32 + row) * 4 + hc;
                red_m[base] = lm; red_s[base] = s;
                red_z[base] = zm; red_i[base] = zi;
            }
        }
    }
    __syncthreads();

    // ---- combine 4 col-quarters per (group,row) ----
    if (tid < 64) {
        const int gg = tid >> 5, r = tid & 31;
        const int b0 = (gg * 32 + r) * 4;
        float m = red_m[b0];
        m = fmaxf(m, red_m[b0 + 1]); m = fmaxf(m, red_m[b0 + 2]); m = fmaxf(m, red_m[b0 + 3]);
        float Z = 0.f;
        float zb = -3.0e38f; int ib = 0;
#pragma unroll
        for (int h = 0; h < 4; ++h) {
            Z += red_s[b0 + h] * __expf(red_m[b0 + h] - m);
            if (red_z[b0 + h] > zb) { zb = red_z[b0 + h]; ib = red_i[b0 + h]; }  // ascending h: first max wins
        }
        idxf[gg * 32 + r]  = ib;
        mfin[gg * 32 + r]  = m;
        wrowS[gg * 32 + r] = ((mask[n0 + r] != 0) ? 1.0f : 0.0f) / Z;
    }
    __syncthreads();

    // ---- marginal: per-col partials over this block's 32 rows ----
    float cs[5] = {0.f, 0.f, 0.f, 0.f, 0.f};
#pragma unroll
    for (int rf = 0; rf < 2; ++rf) {
#pragma unroll
        for (int reg = 0; reg < 4; ++reg) {
            const int row = 16 * rf + 4 * q + reg;
            const float mf = mfin[g * 32 + row], wv = wrowS[g * 32 + row];
#pragma unroll
            for (int cf = 0; cf < 5; ++cf)
                cs[cf] += __expf(acc[rf][cf][reg] - mf) * wv;
        }
    }
#pragma unroll
    for (int cf = 0; cf < 5; ++cf) {
        float v = cs[cf];
        v += __shfl_xor(v, 16);
        v += __shfl_xor(v, 32);
        if (l < 16) atomicAdd(&marg[g * KK + hc * 80 + 16 * cf + l], v);
    }

    // ---- codevector gather ----
    for (int e = tid; e < 32 * 256; e += 512) {
        const int row = e >> 8, c = e & 255, gg = c >> 7, d = c & 127;
        out[(size_t)(n0 + row) * 256 + c] =
            cv[((size_t)gg * KK + idxf[gg * 32 + row]) * DPG + d];
    }
}

// ---------- perplexity finalize ----------
__global__ __launch_bounds__(256) void finalize_kernel(
    const int* __restrict__ mask, const float* __restrict__ marg,
    float* __restrict__ perp_out)
{
    __shared__ float red[256];
    __shared__ float hg[GG];
    const int tid = threadIdx.x;

    int cnt = 0;
    for (int n = tid; n < NN; n += 256) cnt += (mask[n] != 0) ? 1 : 0;
    red[tid] = (float)cnt;
    __syncthreads();
    for (int s = 128; s > 0; s >>= 1) {
        if (tid < s) red[tid] += red[tid + s];
        __syncthreads();
    }
    const float invc = 1.0f / red[0];
    __syncthreads();

    for (int g = 0; g < GG; ++g) {
        float h = 0.0f;
        for (int c = tid; c < KK; c += 256) {
            float m = marg[g * KK + c] * invc;
            h += m * logf(m + EPSL);
        }
        red[tid] = h;
        __syncthreads();
        for (int s = 128; s > 0; s >>= 1) {
            if (tid < s) red[tid] += red[tid + s];
            __syncthreads();
        }
        if (tid == 0) hg[g] = red[0];
        __syncthreads();
    }
    if (tid == 0) perp_out[0] = expf(-hg[0]) + expf(-hg[1]);
}

extern "C" void kernel_launch(void* const* d_in, const int* in_sizes, int n_in,
                              void* d_out, int out_size, void* d_ws, size_t ws_size,
                              hipStream_t stream)
{
    const float* H      = (const float*)d_in[0];   // (32,2048,512) f32
    const int*   mask   = (const int*)d_in[1];     // (32,2048) bool->int32
    const float* gumbel = (const float*)d_in[2];   // (131072,320) f32
    const float* W      = (const float*)d_in[3];   // (640,512) f32
    const float* bias   = (const float*)d_in[4];   // (640,) f32
    const float* cv     = (const float*)d_in[5];   // (1,640,128) f32

    float*  out  = (float*)d_out;                  // 16777216 + 1 floats
    float*  marg = (float*)d_ws;                   // 640 f32 accumulator
    short*  Wf   = (short*)((char*)d_ws + 4096);   // 0.66 MB bf16 frags

    hipMemsetAsync(marg, 0, GG * KK * sizeof(float), stream);
    prep_w<<<160, 256, 0, stream>>>(W, Wf);
    vq_main<<<2048, 512, 0, stream>>>(H, mask, gumbel, Wf, bias, cv, out, marg);
    finalize_kernel<<<1, 256, 0, stream>>>(mask, marg, out + (size_t)NN * GG * DPG);
}